// Round 17
// baseline (62.636 us; speedup 1.0000x reference)
//
#include <hip/hip_runtime.h>
#include <hip/hip_bf16.h>
#include <cstddef>
#include <cstdint>

#define BB    8
#define TT    2048
#define KIN   1024
#define NOUT  512
#define CHUNK 32
#define NCHUNK (TT / CHUNK)   // 64

#define BM 128
#define BN 128
#define BK 32
#define NKSTEP (KIN / BK)     // 32
#define NPAGE  (KIN / 32)     // 32 8KB pages per 128-row strip (W only)
#define TILEB 8192
#define BUFB  24576           // per LDS buffer: A f32 16KB | B f16 8KB

typedef __attribute__((ext_vector_type(4))) float          f32x4;
typedef __attribute__((ext_vector_type(4))) unsigned int   u32x4;
typedef _Float16 f16x8 __attribute__((ext_vector_type(8)));

// ---------------------------------------------------------------------------
// W f32 -> f16 tiled+preswizzled pages (verified R10-R16).  1 MB, ~3 us.
// ---------------------------------------------------------------------------
__global__ __launch_bounds__(256) void conv_tiled_f16(
    const float* __restrict__ src, unsigned char* __restrict__ dst, int total) {
  int idx = blockIdx.x * blockDim.x + threadIdx.x;
  const int stride = gridDim.x * blockDim.x;
  for (; idx < total; idx += stride) {
    const int r  = idx >> 7;
    const int s8 = idx & 127;
    const float* p = src + (size_t)r * KIN + s8 * 8;
    float4 a = *reinterpret_cast<const float4*>(p);
    float4 b = *reinterpret_cast<const float4*>(p + 4);
    f16x8 h;
    h[0] = (_Float16)a.x; h[1] = (_Float16)a.y;
    h[2] = (_Float16)a.z; h[3] = (_Float16)a.w;
    h[4] = (_Float16)b.x; h[5] = (_Float16)b.y;
    h[6] = (_Float16)b.z; h[7] = (_Float16)b.w;
    const int row  = r & 127;
    const int page = (r >> 7) * NPAGE + (s8 >> 2);
    const int slot = (s8 & 3) ^ ((row >> 1) & 3);
    *reinterpret_cast<f16x8*>(dst + (size_t)page * TILEB + row * 64 + slot * 16) = h;
  }
}

#define G2L(gp, sp)                                                        \
  __builtin_amdgcn_global_load_lds(                                       \
      (const __attribute__((address_space(1))) void*)(gp),                \
      (__attribute__((address_space(3))) void*)(sp), 16, 0, 0)

// ---------------------------------------------------------------------------
// fp16 MFMA GEMM — R16 core (dbuf + prefetch-before-compute, 1 barrier/iter)
// + PHASE-STAGGER: block starts its wraparound K-loop at toff=(x*5)&31.
//   Mechanism (R15/R16 post-mortems): co-resident blocks phase-lock — all hit
//   their vmcnt(0) drains simultaneously, CU idles ~700cyc/step.  De-phasing
//   co-resident blocks lets one block's compute cover another's drain (m114).
//   toff depends on x only -> the 4 n-blocks of an m-strip stay in phase and
//   keep A-tile L2 sharing.  K-sum reorder only (fp error unchanged).
// + __launch_bounds__(256,3): 48KB LDS admits exactly 3 blocks/CU (144<=160).
//   A: direct f32 X via inverse-swizzled G2L (R12-verified math);
//   B: pre-swizzled f16 pages (R10-verified); C f16 to ws + fused vend.
//   grid (128 m, 4 n): 128%8==0 -> an m-strip's n-blocks share an XCD.
// ---------------------------------------------------------------------------
__global__ __launch_bounds__(256, 3) void gemm_f16(
    const float* __restrict__ X, const unsigned char* __restrict__ Wt,
    const float* __restrict__ bias, const float* __restrict__ decay,
    unsigned short* __restrict__ Cws, float* __restrict__ vend) {
  __shared__ __align__(16) unsigned char smem[2 * BUFB];  // 48KB

  const int tid  = threadIdx.x;
  const int wave = tid >> 6;
  const int lane = tid & 63;
  const int m0 = blockIdx.x * BM;
  const int n0 = blockIdx.y * BN;
  const int wm = (wave >> 1) * 64;
  const int wn = (wave & 1) * 64;
  const int frow = lane & 15;
  const int g    = lane >> 4;

  // --- A staging map (R12/R16-verified): lane covers row (tid>>3),
  //     slot (tid&7); source slot pre-swizzled so
  //     LDS[row][slot] = X[row][slot^(row&7)] (16B f32 slots). ---
  const int arow  = tid >> 3;          // 0..31
  const int aslot = tid & 7;
  const float* gA = X + (size_t)(m0 + arow) * KIN + ((aslot ^ (arow & 7)) << 2);
  const int ldsw = wave * 1024;

  const unsigned char* srcB = Wt + (size_t)(n0 >> 7) * NPAGE * TILEB + tid * 16;

  const int arswz = frow & 7;
  const int swzr  = (g ^ ((frow >> 1) & 3)) << 4;

  f32x4 acc[4][4] = {};

  auto stage = [&](unsigned char* buf, int t) {
    const int k0 = t * BK;
#pragma unroll
    for (int q = 0; q < 4; ++q)                      // A: 4 x 4KB (32 rows)
      G2L(gA + (size_t)(q * 32) * KIN + k0, buf + q * 4096 + ldsw);
    const size_t boff = (size_t)t * TILEB;           // B: one 8KB page
    G2L(srcB + boff,        buf + 16384 + ldsw);
    G2L(srcB + boff + 4096, buf + 16384 + 4096 + ldsw);
  };

  // phase stagger: x-dependent start step (wraparound); y-independent so the
  // 4 n-blocks of an m-strip stay phase-aligned (A L2 sharing preserved).
  const int toff = (blockIdx.x * 5) & (NKSTEP - 1);

  // prologue: first tile staged and drained
  stage(smem, toff);
  __syncthreads();

  for (int i = 0; i < NKSTEP; ++i) {
    const int t = (i + toff) & (NKSTEP - 1);
    unsigned char* cur = smem + (i & 1) * BUFB;
    unsigned char* nxt = smem + ((i + 1) & 1) * BUFB;

    // 1) issue next tile FIRST (flies under this iter's compute)
    if (i + 1 < NKSTEP) stage(nxt, (t + 1) & (NKSTEP - 1));

    // 2) compute(t): A f32 -> pkrtz f16 fragments; B f16 fragments; 16 MFMA
    f16x8 af[4];
#pragma unroll
    for (int mi = 0; mi < 4; ++mi) {
      const int row = wm + mi * 16 + frow;
      const unsigned char* ap = cur + row * 128;
      const int s0 = g * 2;
      f32x4 q0 = *reinterpret_cast<const f32x4*>(ap + ((s0)     ^ arswz) * 16);
      f32x4 q1 = *reinterpret_cast<const f32x4*>(ap + ((s0 + 1) ^ arswz) * 16);
      u32x4 hv;
      hv[0] = __builtin_bit_cast(unsigned int, __builtin_amdgcn_cvt_pkrtz(q0[0], q0[1]));
      hv[1] = __builtin_bit_cast(unsigned int, __builtin_amdgcn_cvt_pkrtz(q0[2], q0[3]));
      hv[2] = __builtin_bit_cast(unsigned int, __builtin_amdgcn_cvt_pkrtz(q1[0], q1[1]));
      hv[3] = __builtin_bit_cast(unsigned int, __builtin_amdgcn_cvt_pkrtz(q1[2], q1[3]));
      af[mi] = __builtin_bit_cast(f16x8, hv);
    }
#pragma unroll
    for (int ni = 0; ni < 4; ++ni) {
      f16x8 bf = *reinterpret_cast<const f16x8*>(
          cur + 16384 + (wn + ni * 16 + frow) * 64 + swzr);
#pragma unroll
      for (int mi = 0; mi < 4; ++mi)
        acc[mi][ni] = __builtin_amdgcn_mfma_f32_16x16x32_f16(af[mi], bf, acc[mi][ni], 0, 0, 0);
    }

    // 3) one barrier: drains stage(t+1) (flew under compute) + LDS reads
    __syncthreads();
  }

  // --- epilogue: bias + f16 C store to workspace (verified R11-R16) ---
  const int colb = n0 + wn + frow;
  const int rowb = m0 + wm + (g << 2);
  float bv[4];
#pragma unroll
  for (int ni = 0; ni < 4; ++ni) bv[ni] = bias[colb + ni * 16];
#pragma unroll
  for (int mi = 0; mi < 4; ++mi) {
#pragma unroll
    for (int r = 0; r < 4; ++r) {
#pragma unroll
      for (int ni = 0; ni < 4; ++ni) {
        const _Float16 hv = (_Float16)(acc[mi][ni][r] + bv[ni]);
        Cws[(size_t)(rowb + mi * 16 + r) * NOUT + colb + ni * 16] =
            __builtin_bit_cast(unsigned short, hv);
      }
    }
  }

  // --- fused vend: Horner + shfl (verified R8/R10-R16) ---
  {
    float rlo[4], rhi[4];
#pragma unroll
    for (int ni = 0; ni < 4; ++ni) {
      const float d  = decay[colb + ni * 16];
      const float bb = bv[ni];
      const float omd = 1.0f - d;
      const float dd = d * d, d4 = dd * dd, d8 = d4 * d4;
      const float d16 = d8 * d8, d12 = d8 * d4;
      const float dpg = (g == 0) ? d12 : (g == 1) ? d8 : (g == 2) ? d4 : 1.0f;
      float s[4];
#pragma unroll
      for (int mi = 0; mi < 4; ++mi) {
        float v = acc[mi][ni][0] + bb;
        v = v * d + (acc[mi][ni][1] + bb);
        v = v * d + (acc[mi][ni][2] + bb);
        v = v * d + (acc[mi][ni][3] + bb);
        s[mi] = omd * v;
      }
      float ulo = dpg * (s[0] * d16 + s[1]);
      float uhi = dpg * (s[2] * d16 + s[3]);
      ulo += __shfl_xor(ulo, 16); ulo += __shfl_xor(ulo, 32);
      uhi += __shfl_xor(uhi, 16); uhi += __shfl_xor(uhi, 32);
      rlo[ni] = ulo; rhi[ni] = uhi;
    }
    const int b   = m0 >> 11;
    const int clo = ((m0 & (TT - 1)) >> 5) + (wm >> 5);
    const int chunk = clo + (g >> 1);
    const int half  = g >> 1;
    const int nia   = g & 1;
    const float v1 = half ? (nia ? rhi[1] : rhi[0]) : (nia ? rlo[1] : rlo[0]);
    const float v2 = half ? (nia ? rhi[3] : rhi[2]) : (nia ? rlo[3] : rlo[2]);
    const int col1 = n0 + wn + frow + nia * 16;
    float* vp = vend + ((size_t)b * NCHUNK + chunk) * NOUT;
    vp[col1]      = v1;
    vp[col1 + 32] = v2;
  }
}

// ---------------------------------------------------------------------------
// Fallback f32 GEMM (verified R1) — only if workspace is too small.
// ---------------------------------------------------------------------------
__global__ __launch_bounds__(256) void gemm_f32_64x64(
    const float* __restrict__ X, const float* __restrict__ W,
    const float* __restrict__ bias, float* __restrict__ C) {
  __shared__ float As[16][65];
  __shared__ float Bs[16][65];
  const int m0  = blockIdx.y * 64;
  const int n0  = blockIdx.x * 64;
  const int tid = threadIdx.x;
  const int tx  = tid & 15;
  const int ty  = tid >> 4;
  const int lr  = tid >> 2;
  const int lk  = (tid & 3) << 2;
  float acc[4][4] = {};
  const float* xa = X + (size_t)(m0 + lr) * KIN + lk;
  const float* wb = W + (size_t)(n0 + lr) * KIN + lk;
  for (int k0 = 0; k0 < KIN; k0 += 16) {
    float4 av = *reinterpret_cast<const float4*>(xa + k0);
    float4 bv = *reinterpret_cast<const float4*>(wb + k0);
    As[lk + 0][lr] = av.x; As[lk + 1][lr] = av.y;
    As[lk + 2][lr] = av.z; As[lk + 3][lr] = av.w;
    Bs[lk + 0][lr] = bv.x; Bs[lk + 1][lr] = bv.y;
    Bs[lk + 2][lr] = bv.z; Bs[lk + 3][lr] = bv.w;
    __syncthreads();
#pragma unroll
    for (int k = 0; k < 16; ++k) {
      float a[4], b[4];
#pragma unroll
      for (int i = 0; i < 4; ++i) a[i] = As[k][ty * 4 + i];
#pragma unroll
      for (int j = 0; j < 4; ++j) b[j] = Bs[k][tx * 4 + j];
#pragma unroll
      for (int i = 0; i < 4; ++i)
#pragma unroll
        for (int j = 0; j < 4; ++j) acc[i][j] += a[i] * b[j];
    }
    __syncthreads();
  }
  const int n = n0 + tx * 4;
  float4 bv = *reinterpret_cast<const float4*>(&bias[n]);
#pragma unroll
  for (int i = 0; i < 4; ++i) {
    const int m = m0 + ty * 4 + i;
    float4 r;
    r.x = acc[i][0] + bv.x; r.y = acc[i][1] + bv.y;
    r.z = acc[i][2] + bv.z; r.w = acc[i][3] + bv.w;
    *reinterpret_cast<float4*>(&C[(size_t)m * NOUT + n]) = r;
  }
}

// ---------------------------------------------------------------------------
// Fixup with integrated chunk-carry compose (verified R11-R16): block (b,c)
// composes vinit from vend, scans its chunk from f16 Cws, writes out+states.
// ---------------------------------------------------------------------------
__global__ __launch_bounds__(512) void scan_fixup2(
    const unsigned short* __restrict__ Cws, const float* __restrict__ vend,
    const float* __restrict__ decay, float* __restrict__ out,
    float* __restrict__ states) {
  const int b = blockIdx.x / NCHUNK;
  const int c = blockIdx.x % NCHUNK;
  const int o = threadIdx.x;
  const float d   = decay[o];
  const float omd = 1.0f - d;
  const float dd = d * d, d4 = dd * dd, d8 = d4 * d4, d16 = d8 * d8;
  const float dL = d16 * d16;   // d^CHUNK

  float v = 0.0f;
  const float* vp = vend + (size_t)b * NCHUNK * NOUT + o;
  for (int cc = 0; cc < c; ++cc) v = dL * v + vp[(size_t)cc * NOUT];

  size_t obase = ((size_t)b * TT + (size_t)c * CHUNK) * NOUT + o;
  size_t sbase = ((size_t)b * (TT + 1) + (size_t)c * CHUNK + 1) * NOUT + o;
#pragma unroll 4
  for (int k = 0; k < CHUNK; ++k) {
    const unsigned short hu = Cws[obase + (size_t)k * NOUT];
    const float cur = (float)__builtin_bit_cast(_Float16, hu);
    v = d * v + omd * cur;
    out[obase + (size_t)k * NOUT]    = v;
    states[sbase + (size_t)k * NOUT] = v;
  }
  if (c == 0) states[((size_t)b * (TT + 1)) * NOUT + o] = 0.0f;
}

__global__ __launch_bounds__(512) void scan_seq(
    float* __restrict__ C, float* __restrict__ states,
    const float* __restrict__ decay) {
  const int b = blockIdx.x;
  const int o = threadIdx.x;
  const float d   = decay[o];
  const float omd = 1.0f - d;
  float v = 0.0f;
  states[((size_t)b * (TT + 1)) * NOUT + o] = 0.0f;
  for (int t = 0; t < TT; ++t) {
    const size_t oi = ((size_t)b * TT + t) * NOUT + o;
    float x = C[oi];
    v = d * v + omd * x;
    C[oi] = v;
    states[((size_t)b * (TT + 1) + t + 1) * NOUT + o] = v;
  }
}

extern "C" void kernel_launch(void* const* d_in, const int* in_sizes, int n_in,
                              void* d_out, int out_size, void* d_ws, size_t ws_size,
                              hipStream_t stream) {
  const float* x     = (const float*)d_in[0];  // [B,T,IN]
  const float* w     = (const float*)d_in[1];  // [OUT,IN]
  const float* bias  = (const float*)d_in[2];  // [OUT]
  const float* decay = (const float*)d_in[3];  // [OUT]

  float* out    = (float*)d_out;                 // [B,T,OUT]
  float* states = out + (size_t)BB * TT * NOUT;  // [1,B,T+1,OUT]

  const size_t szWb = (size_t)NOUT * KIN * sizeof(_Float16);        // 1 MB
  const size_t szCb = (size_t)BB * TT * NOUT * sizeof(_Float16);    // 16.8 MB
  const size_t scan_elems = (size_t)BB * NCHUNK * NOUT;
  const size_t need = szWb + szCb + scan_elems * sizeof(float);     // ~20 MB

  if (ws_size >= need) {
    unsigned char*  Wt   = (unsigned char*)d_ws;
    unsigned short* Cws  = (unsigned short*)(Wt + szWb);
    float*          vend = (float*)(Cws + (size_t)BB * TT * NOUT);

    conv_tiled_f16<<<256, 256, 0, stream>>>(w, Wt, NOUT * (KIN / 8));
    gemm_f16<<<dim3((BB * TT) / BM, NOUT / BN), 256, 0, stream>>>(
        x, Wt, bias, decay, Cws, vend);
    scan_fixup2<<<BB * NCHUNK, NOUT, 0, stream>>>(Cws, vend, decay, out, states);
  } else {
    gemm_f32_64x64<<<dim3(NOUT / 64, (BB * TT) / 64), 256, 0, stream>>>(x, w, bias, out);
    scan_seq<<<BB, NOUT, 0, stream>>>(out, states, decay);
  }
}

// Round 18
// 62.267 us; speedup vs baseline: 1.0059x; 1.0059x over previous
//
#include <hip/hip_runtime.h>
#include <hip/hip_bf16.h>
#include <cstddef>
#include <cstdint>

#define BB    8
#define TT    2048
#define KIN   1024
#define NOUT  512
#define CHUNK 32
#define NCHUNK (TT / CHUNK)   // 64

#define BM 128
#define BN 128
#define BK 32
#define NKSTEP (KIN / BK)     // 32
#define NPAGE  (KIN / 32)     // 32 8KB pages per 128-row strip (W only)
#define TILEB 8192
#define BUFB  24576           // per LDS buffer: A f32 16KB | B f16 8KB

typedef __attribute__((ext_vector_type(4))) float          f32x4;
typedef __attribute__((ext_vector_type(4))) unsigned int   u32x4;
typedef _Float16 f16x8 __attribute__((ext_vector_type(8)));

// ---------------------------------------------------------------------------
// W f32 -> f16 tiled+preswizzled pages (verified R10-R17).  1 MB, ~3 us.
// ---------------------------------------------------------------------------
__global__ __launch_bounds__(256) void conv_tiled_f16(
    const float* __restrict__ src, unsigned char* __restrict__ dst, int total) {
  int idx = blockIdx.x * blockDim.x + threadIdx.x;
  const int stride = gridDim.x * blockDim.x;
  for (; idx < total; idx += stride) {
    const int r  = idx >> 7;
    const int s8 = idx & 127;
    const float* p = src + (size_t)r * KIN + s8 * 8;
    float4 a = *reinterpret_cast<const float4*>(p);
    float4 b = *reinterpret_cast<const float4*>(p + 4);
    f16x8 h;
    h[0] = (_Float16)a.x; h[1] = (_Float16)a.y;
    h[2] = (_Float16)a.z; h[3] = (_Float16)a.w;
    h[4] = (_Float16)b.x; h[5] = (_Float16)b.y;
    h[6] = (_Float16)b.z; h[7] = (_Float16)b.w;
    const int row  = r & 127;
    const int page = (r >> 7) * NPAGE + (s8 >> 2);
    const int slot = (s8 & 3) ^ ((row >> 1) & 3);
    *reinterpret_cast<f16x8*>(dst + (size_t)page * TILEB + row * 64 + slot * 16) = h;
  }
}

#define G2L(gp, sp)                                                        \
  __builtin_amdgcn_global_load_lds(                                       \
      (const __attribute__((address_space(1))) void*)(gp),                \
      (__attribute__((address_space(3))) void*)(sp), 16, 0, 0)

// ---------------------------------------------------------------------------
// fp16 MFMA GEMM — R16's verified data path + TRUE counted-vmcnt pipeline
// (T4, the one mechanism not yet tried cleanly):
//   TRIPLE-buffered LDS (3x24KB=72KB).  Prologue stages tiles 0,1,2
//   (18 G2L/thread in flight).  Per iter t:
//     s_waitcnt vmcnt(12)   <- stage(t) landed; t+1,t+2 STAY IN FLIGHT
//     s_barrier             <- buf ready for all waves
//     compute(t)            <- ds_read + pkrtz + 16 MFMA (compiler lgkm)
//     s_waitcnt lgkmcnt(0); s_barrier   <- reads done; NO vmcnt drain
//     stage(t+3) into freed buffer
//   Loads get ~3 steps (~1000+cyc) to land vs R16's ~250cyc -> drain hidden.
//   No sched_barrier (m141 poison), no __syncthreads (forces vmcnt(0)).
//   Race-safety: vmcnt FIFO (m135); G2L/ds_read are memory ops and cannot
//   cross "memory"-clobbered asm; buffer rewritten only after barrier2.
//   Data path byte-identical to R16 (passed): A = direct f32 X inverse-
//   swizzled G2L, B = pre-swizzled f16 pages, C f16 to ws + fused vend.
//   grid (128 m, 4 n): 128%8==0 -> an m-strip's n-blocks share an XCD.
// ---------------------------------------------------------------------------
__global__ __launch_bounds__(256, 2) void gemm_f16(
    const float* __restrict__ X, const unsigned char* __restrict__ Wt,
    const float* __restrict__ bias, const float* __restrict__ decay,
    unsigned short* __restrict__ Cws, float* __restrict__ vend) {
  __shared__ __align__(16) unsigned char smem[3 * BUFB];  // 72KB

  const int tid  = threadIdx.x;
  const int wave = tid >> 6;
  const int lane = tid & 63;
  const int m0 = blockIdx.x * BM;
  const int n0 = blockIdx.y * BN;
  const int wm = (wave >> 1) * 64;
  const int wn = (wave & 1) * 64;
  const int frow = lane & 15;
  const int g    = lane >> 4;

  // --- A staging map (R12/R16-verified): lane covers row (tid>>3),
  //     slot (tid&7); source slot pre-swizzled so
  //     LDS[row][slot] = X[row][slot^(row&7)] (16B f32 slots). ---
  const int arow  = tid >> 3;          // 0..31
  const int aslot = tid & 7;
  const float* gA = X + (size_t)(m0 + arow) * KIN + ((aslot ^ (arow & 7)) << 2);
  const int ldsw = wave * 1024;

  const unsigned char* srcB = Wt + (size_t)(n0 >> 7) * NPAGE * TILEB + tid * 16;

  const int arswz = frow & 7;
  const int swzr  = (g ^ ((frow >> 1) & 3)) << 4;

  f32x4 acc[4][4] = {};

  auto stage = [&](unsigned char* buf, int t) {
    const int k0 = t * BK;
#pragma unroll
    for (int q = 0; q < 4; ++q)                      // A: 4 x 4KB (32 rows)
      G2L(gA + (size_t)(q * 32) * KIN + k0, buf + q * 4096 + ldsw);
    const size_t boff = (size_t)t * TILEB;           // B: one 8KB page
    G2L(srcB + boff,        buf + 16384 + ldsw);
    G2L(srcB + boff + 4096, buf + 16384 + 4096 + ldsw);
  };

  // rotating buffer pointers (registers, no runtime-indexed array)
  unsigned char* bufA = smem;
  unsigned char* bufB = smem + BUFB;
  unsigned char* bufC = smem + 2 * BUFB;

  // prologue: 3 tiles in flight (18 G2L/thread outstanding)
  stage(bufA, 0);
  stage(bufB, 1);
  stage(bufC, 2);

  for (int t = 0; t < NKSTEP; ++t) {
    // wait for stage(t) ONLY; stages t+1,t+2 remain in flight
    if (t < NKSTEP - 2)
      asm volatile("s_waitcnt vmcnt(12)" ::: "memory");
    else if (t == NKSTEP - 2)
      asm volatile("s_waitcnt vmcnt(6)" ::: "memory");
    else
      asm volatile("s_waitcnt vmcnt(0)" ::: "memory");
    __builtin_amdgcn_s_barrier();       // buf[t%3] ready block-wide

    // compute(t): A f32 -> pkrtz f16 fragments; B f16 fragments; 16 MFMA
    f16x8 af[4];
#pragma unroll
    for (int mi = 0; mi < 4; ++mi) {
      const int row = wm + mi * 16 + frow;
      const unsigned char* ap = bufA + row * 128;
      const int s0 = g * 2;
      f32x4 q0 = *reinterpret_cast<const f32x4*>(ap + ((s0)     ^ arswz) * 16);
      f32x4 q1 = *reinterpret_cast<const f32x4*>(ap + ((s0 + 1) ^ arswz) * 16);
      u32x4 hv;
      hv[0] = __builtin_bit_cast(unsigned int, __builtin_amdgcn_cvt_pkrtz(q0[0], q0[1]));
      hv[1] = __builtin_bit_cast(unsigned int, __builtin_amdgcn_cvt_pkrtz(q0[2], q0[3]));
      hv[2] = __builtin_bit_cast(unsigned int, __builtin_amdgcn_cvt_pkrtz(q1[0], q1[1]));
      hv[3] = __builtin_bit_cast(unsigned int, __builtin_amdgcn_cvt_pkrtz(q1[2], q1[3]));
      af[mi] = __builtin_bit_cast(f16x8, hv);
    }
#pragma unroll
    for (int ni = 0; ni < 4; ++ni) {
      f16x8 bf = *reinterpret_cast<const f16x8*>(
          bufA + 16384 + (wn + ni * 16 + frow) * 64 + swzr);
#pragma unroll
      for (int mi = 0; mi < 4; ++mi)
        acc[mi][ni] = __builtin_amdgcn_mfma_f32_16x16x32_f16(af[mi], bf, acc[mi][ni], 0, 0, 0);
    }

    // reads complete (lgkm only — vmcnt NOT drained), then free the buffer
    asm volatile("s_waitcnt lgkmcnt(0)" ::: "memory");
    __builtin_amdgcn_s_barrier();

    // refill freed buffer with tile t+3 (lands ~3 steps from now)
    if (t + 3 < NKSTEP) stage(bufA, t + 3);

    // rotate
    unsigned char* tmp = bufA; bufA = bufB; bufB = bufC; bufC = tmp;
  }

  // --- epilogue: bias + f16 C store to workspace (verified R11-R17) ---
  const int colb = n0 + wn + frow;
  const int rowb = m0 + wm + (g << 2);
  float bv[4];
#pragma unroll
  for (int ni = 0; ni < 4; ++ni) bv[ni] = bias[colb + ni * 16];
#pragma unroll
  for (int mi = 0; mi < 4; ++mi) {
#pragma unroll
    for (int r = 0; r < 4; ++r) {
#pragma unroll
      for (int ni = 0; ni < 4; ++ni) {
        const _Float16 hv = (_Float16)(acc[mi][ni][r] + bv[ni]);
        Cws[(size_t)(rowb + mi * 16 + r) * NOUT + colb + ni * 16] =
            __builtin_bit_cast(unsigned short, hv);
      }
    }
  }

  // --- fused vend: Horner + shfl (verified R8/R10-R17) ---
  {
    float rlo[4], rhi[4];
#pragma unroll
    for (int ni = 0; ni < 4; ++ni) {
      const float d  = decay[colb + ni * 16];
      const float bb = bv[ni];
      const float omd = 1.0f - d;
      const float dd = d * d, d4 = dd * dd, d8 = d4 * d4;
      const float d16 = d8 * d8, d12 = d8 * d4;
      const float dpg = (g == 0) ? d12 : (g == 1) ? d8 : (g == 2) ? d4 : 1.0f;
      float s[4];
#pragma unroll
      for (int mi = 0; mi < 4; ++mi) {
        float v = acc[mi][ni][0] + bb;
        v = v * d + (acc[mi][ni][1] + bb);
        v = v * d + (acc[mi][ni][2] + bb);
        v = v * d + (acc[mi][ni][3] + bb);
        s[mi] = omd * v;
      }
      float ulo = dpg * (s[0] * d16 + s[1]);
      float uhi = dpg * (s[2] * d16 + s[3]);
      ulo += __shfl_xor(ulo, 16); ulo += __shfl_xor(ulo, 32);
      uhi += __shfl_xor(uhi, 16); uhi += __shfl_xor(uhi, 32);
      rlo[ni] = ulo; rhi[ni] = uhi;
    }
    const int b   = m0 >> 11;
    const int clo = ((m0 & (TT - 1)) >> 5) + (wm >> 5);
    const int chunk = clo + (g >> 1);
    const int half  = g >> 1;
    const int nia   = g & 1;
    const float v1 = half ? (nia ? rhi[1] : rhi[0]) : (nia ? rlo[1] : rlo[0]);
    const float v2 = half ? (nia ? rhi[3] : rhi[2]) : (nia ? rlo[3] : rlo[2]);
    const int col1 = n0 + wn + frow + nia * 16;
    float* vp = vend + ((size_t)b * NCHUNK + chunk) * NOUT;
    vp[col1]      = v1;
    vp[col1 + 32] = v2;
  }
}

// ---------------------------------------------------------------------------
// Fallback f32 GEMM (verified R1) — only if workspace is too small.
// ---------------------------------------------------------------------------
__global__ __launch_bounds__(256) void gemm_f32_64x64(
    const float* __restrict__ X, const float* __restrict__ W,
    const float* __restrict__ bias, float* __restrict__ C) {
  __shared__ float As[16][65];
  __shared__ float Bs[16][65];
  const int m0  = blockIdx.y * 64;
  const int n0  = blockIdx.x * 64;
  const int tid = threadIdx.x;
  const int tx  = tid & 15;
  const int ty  = tid >> 4;
  const int lr  = tid >> 2;
  const int lk  = (tid & 3) << 2;
  float acc[4][4] = {};
  const float* xa = X + (size_t)(m0 + lr) * KIN + lk;
  const float* wb = W + (size_t)(n0 + lr) * KIN + lk;
  for (int k0 = 0; k0 < KIN; k0 += 16) {
    float4 av = *reinterpret_cast<const float4*>(xa + k0);
    float4 bv = *reinterpret_cast<const float4*>(wb + k0);
    As[lk + 0][lr] = av.x; As[lk + 1][lr] = av.y;
    As[lk + 2][lr] = av.z; As[lk + 3][lr] = av.w;
    Bs[lk + 0][lr] = bv.x; Bs[lk + 1][lr] = bv.y;
    Bs[lk + 2][lr] = bv.z; Bs[lk + 3][lr] = bv.w;
    __syncthreads();
#pragma unroll
    for (int k = 0; k < 16; ++k) {
      float a[4], b[4];
#pragma unroll
      for (int i = 0; i < 4; ++i) a[i] = As[k][ty * 4 + i];
#pragma unroll
      for (int j = 0; j < 4; ++j) b[j] = Bs[k][tx * 4 + j];
#pragma unroll
      for (int i = 0; i < 4; ++i)
#pragma unroll
        for (int j = 0; j < 4; ++j) acc[i][j] += a[i] * b[j];
    }
    __syncthreads();
  }
  const int n = n0 + tx * 4;
  float4 bv = *reinterpret_cast<const float4*>(&bias[n]);
#pragma unroll
  for (int i = 0; i < 4; ++i) {
    const int m = m0 + ty * 4 + i;
    float4 r;
    r.x = acc[i][0] + bv.x; r.y = acc[i][1] + bv.y;
    r.z = acc[i][2] + bv.z; r.w = acc[i][3] + bv.w;
    *reinterpret_cast<float4*>(&C[(size_t)m * NOUT + n]) = r;
  }
}

// ---------------------------------------------------------------------------
// Fixup with integrated chunk-carry compose (verified R11-R17): block (b,c)
// composes vinit from vend, scans its chunk from f16 Cws, writes out+states.
// ---------------------------------------------------------------------------
__global__ __launch_bounds__(512) void scan_fixup2(
    const unsigned short* __restrict__ Cws, const float* __restrict__ vend,
    const float* __restrict__ decay, float* __restrict__ out,
    float* __restrict__ states) {
  const int b = blockIdx.x / NCHUNK;
  const int c = blockIdx.x % NCHUNK;
  const int o = threadIdx.x;
  const float d   = decay[o];
  const float omd = 1.0f - d;
  const float dd = d * d, d4 = dd * dd, d8 = d4 * d4, d16 = d8 * d8;
  const float dL = d16 * d16;   // d^CHUNK

  float v = 0.0f;
  const float* vp = vend + (size_t)b * NCHUNK * NOUT + o;
  for (int cc = 0; cc < c; ++cc) v = dL * v + vp[(size_t)cc * NOUT];

  size_t obase = ((size_t)b * TT + (size_t)c * CHUNK) * NOUT + o;
  size_t sbase = ((size_t)b * (TT + 1) + (size_t)c * CHUNK + 1) * NOUT + o;
#pragma unroll 4
  for (int k = 0; k < CHUNK; ++k) {
    const unsigned short hu = Cws[obase + (size_t)k * NOUT];
    const float cur = (float)__builtin_bit_cast(_Float16, hu);
    v = d * v + omd * cur;
    out[obase + (size_t)k * NOUT]    = v;
    states[sbase + (size_t)k * NOUT] = v;
  }
  if (c == 0) states[((size_t)b * (TT + 1)) * NOUT + o] = 0.0f;
}

__global__ __launch_bounds__(512) void scan_seq(
    float* __restrict__ C, float* __restrict__ states,
    const float* __restrict__ decay) {
  const int b = blockIdx.x;
  const int o = threadIdx.x;
  const float d   = decay[o];
  const float omd = 1.0f - d;
  float v = 0.0f;
  states[((size_t)b * (TT + 1)) * NOUT + o] = 0.0f;
  for (int t = 0; t < TT; ++t) {
    const size_t oi = ((size_t)b * TT + t) * NOUT + o;
    float x = C[oi];
    v = d * v + omd * x;
    C[oi] = v;
    states[((size_t)b * (TT + 1) + t + 1) * NOUT + o] = v;
  }
}

extern "C" void kernel_launch(void* const* d_in, const int* in_sizes, int n_in,
                              void* d_out, int out_size, void* d_ws, size_t ws_size,
                              hipStream_t stream) {
  const float* x     = (const float*)d_in[0];  // [B,T,IN]
  const float* w     = (const float*)d_in[1];  // [OUT,IN]
  const float* bias  = (const float*)d_in[2];  // [OUT]
  const float* decay = (const float*)d_in[3];  // [OUT]

  float* out    = (float*)d_out;                 // [B,T,OUT]
  float* states = out + (size_t)BB * TT * NOUT;  // [1,B,T+1,OUT]

  const size_t szWb = (size_t)NOUT * KIN * sizeof(_Float16);        // 1 MB
  const size_t szCb = (size_t)BB * TT * NOUT * sizeof(_Float16);    // 16.8 MB
  const size_t scan_elems = (size_t)BB * NCHUNK * NOUT;
  const size_t need = szWb + szCb + scan_elems * sizeof(float);     // ~20 MB

  if (ws_size >= need) {
    unsigned char*  Wt   = (unsigned char*)d_ws;
    unsigned short* Cws  = (unsigned short*)(Wt + szWb);
    float*          vend = (float*)(Cws + (size_t)BB * TT * NOUT);

    conv_tiled_f16<<<256, 256, 0, stream>>>(w, Wt, NOUT * (KIN / 8));
    gemm_f16<<<dim3((BB * TT) / BM, NOUT / BN), 256, 0, stream>>>(
        x, Wt, bias, decay, Cws, vend);
    scan_fixup2<<<BB * NCHUNK, NOUT, 0, stream>>>(Cws, vend, decay, out, states);
  } else {
    gemm_f32_64x64<<<dim3(NOUT / 64, (BB * TT) / 64), 256, 0, stream>>>(x, w, bias, out);
    scan_seq<<<BB, NOUT, 0, stream>>>(out, states, decay);
  }
}